// Round 1
// 1062.124 us; speedup vs baseline: 1.1459x; 1.1459x over previous
//
#include <hip/hip_runtime.h>

#define N_NODES 100000
#define N_EDGES 1200000
#define R_REL 3
#define RN (R_REL * N_NODES)   // 300000
#define RE (R_REL * N_EDGES)   // 3600000

__device__ __forceinline__ float bcast(float v, int l) {
  return __int_as_float(__builtin_amdgcn_readlane(__float_as_int(v), l));
}

// ---------------- CSR build ----------------
__global__ void k_zero(int* p, int n) {
  int i = blockIdx.x * 256 + threadIdx.x;
  if (i < n) p[i] = 0;
}

__global__ void k_count(const int* __restrict__ dst, int* __restrict__ deg) {
  int i = blockIdx.x * 256 + threadIdx.x;
  if (i < RE) {
    int r = i / N_EDGES;
    atomicAdd(&deg[r * N_NODES + dst[i]], 1);
  }
}

__global__ void k_scan1(const int* __restrict__ deg, int* __restrict__ P,
                        int* __restrict__ bsums) {
  __shared__ int sd[256];
  int t = threadIdx.x;
  int base = blockIdx.x * 2048 + t * 8;
  int v[8];
  int tot = 0;
#pragma unroll
  for (int q = 0; q < 8; q++) {
    v[q] = (base + q < RN) ? deg[base + q] : 0;
    tot += v[q];
  }
  sd[t] = tot;
  __syncthreads();
  for (int off = 1; off < 256; off <<= 1) {
    int x = (t >= off) ? sd[t - off] : 0;
    __syncthreads();
    sd[t] += x;
    __syncthreads();
  }
  int run = sd[t] - tot;  // exclusive prefix within chunk
#pragma unroll
  for (int q = 0; q < 8; q++) {
    if (base + q < RN) P[base + q] = run;
    run += v[q];
  }
  if (t == 255) bsums[blockIdx.x] = sd[255];
}

__global__ void k_scan2(const int* __restrict__ bsums, int* __restrict__ boffs, int nb) {
  __shared__ int sd[256];
  int t = threadIdx.x;
  int v = (t < nb) ? bsums[t] : 0;
  sd[t] = v;
  __syncthreads();
  for (int off = 1; off < 256; off <<= 1) {
    int x = (t >= off) ? sd[t - off] : 0;
    __syncthreads();
    sd[t] += x;
    __syncthreads();
  }
  if (t < nb) boffs[t] = sd[t] - v;
}

__global__ void k_scan3(int* __restrict__ P, int* __restrict__ cursor,
                        const int* __restrict__ boffs) {
  int i = blockIdx.x * 256 + threadIdx.x;
  if (i < RN) {
    int p = P[i] + boffs[i >> 11];
    P[i] = p;
    cursor[i] = p;
  }
}

__global__ void k_scatter(const int* __restrict__ src, const int* __restrict__ dst,
                          int* __restrict__ cursor, int* __restrict__ ssrc) {
  int i = blockIdx.x * 256 + threadIdx.x;
  if (i < RE) {
    int r = i / N_EDGES;
    int p = atomicAdd(&cursor[r * N_NODES + dst[i]], 1);
    ssrc[p] = src[i];
  }
}

// ---------------- node transforms ----------------
// hp[r][n][64] = h@w_w[r]+w_b[r]
// pk[r][n][8]  = { asrc[4 heads], sdot, -, -, - }  (32B packed per (r,n))
//   asrc[h] = dot(hp_head, wa0) + dot(es_head, wa2) + atten_b[r]
//   sdot    = dot(es[n], beta_r[0:64])   (gate es-part, distributed over seg-sum)
// adst[r][n][4] = per-head dst attention part
__global__ __launch_bounds__(256) void k_node(
    const float* __restrict__ h, const float* __restrict__ d_w,
    const float* __restrict__ d_b, const float* __restrict__ w_w,
    const float* __restrict__ w_b, const float* __restrict__ atten_w,
    const float* __restrict__ atten_b, const float* __restrict__ beta,
    float* __restrict__ hp, float* __restrict__ pk, float* __restrict__ adst) {
  __shared__ float sW[4 * 4096];  // 64 KB: d_w, w_w[0..2], layout [m][k*64+c]
  int tid = threadIdx.x;
  for (int idx = tid; idx < 4096; idx += 256) {
    sW[idx] = d_w[idx];
    sW[4096 + idx] = w_w[idx];
    sW[8192 + idx] = w_w[4096 + idx];
    sW[12288 + idx] = w_w[8192 + idx];
  }
  __syncthreads();
  int lane = tid & 63, wid = tid >> 6;
  int wave = blockIdx.x * 4 + wid, nw = gridDim.x * 4;
  int k16 = lane & 15, hgrp = lane >> 4;
  float dbv = d_b[lane];
  float wbv0 = w_b[lane], wbv1 = w_b[64 + lane], wbv2 = w_b[128 + lane];
  float wa0[3], wa1[3], wa2[3], ab[3], bb[3];
#pragma unroll
  for (int r = 0; r < 3; r++) {
    wa0[r] = atten_w[r * 48 + k16];
    wa1[r] = atten_w[r * 48 + 16 + k16];
    wa2[r] = atten_w[r * 48 + 32 + k16];
    ab[r] = atten_b[r];
    bb[r] = beta[r * 128 + lane];  // es-part of gate beta
  }
  for (int g = wave; g < N_NODES / 8; g += nw) {
    int n0 = g * 8;
    float hr[8];
#pragma unroll
    for (int i = 0; i < 8; i++) hr[i] = h[(n0 + i) * 64 + lane];
    float acc[8][4];
#pragma unroll
    for (int i = 0; i < 8; i++) {
      acc[i][0] = dbv; acc[i][1] = wbv0; acc[i][2] = wbv1; acc[i][3] = wbv2;
    }
#pragma unroll 4
    for (int k = 0; k < 64; k++) {
      float w0 = sW[k * 64 + lane];
      float w1 = sW[4096 + k * 64 + lane];
      float w2 = sW[8192 + k * 64 + lane];
      float w3 = sW[12288 + k * 64 + lane];
#pragma unroll
      for (int i = 0; i < 8; i++) {
        float a = bcast(hr[i], k);
        acc[i][0] += a * w0; acc[i][1] += a * w1;
        acc[i][2] += a * w2; acc[i][3] += a * w3;
      }
    }
#pragma unroll
    for (int i = 0; i < 8; i++) {
      int n = n0 + i;
      float esv = tanhf(2.f * acc[i][0]);
#pragma unroll
      for (int r = 0; r < 3; r++) {
        int idxrn = r * N_NODES + n;
        float hpv = acc[i][1 + r];
        hp[(size_t)idxrn * 64 + lane] = hpv;
        float cs = hpv * wa0[r] + esv * wa2[r];
        float cd = hpv * wa1[r];
#pragma unroll
        for (int m = 1; m < 16; m <<= 1) {
          cs += __shfl_xor(cs, m);
          cd += __shfl_xor(cd, m);
        }
        float sv = esv * bb[r];
#pragma unroll
        for (int m = 1; m < 64; m <<= 1) sv += __shfl_xor(sv, m);
        if (k16 == 0) {
          pk[(size_t)idxrn * 8 + hgrp] = cs + ab[r];
          adst[(size_t)idxrn * 4 + hgrp] = cd;
        }
        if (lane == 0) pk[(size_t)idxrn * 8 + 4] = sv;
      }
    }
  }
}

// ---------------- fused: per-dst softmax-aggregate + gate + final linear ----------------
__global__ __launch_bounds__(512) void k_fused(
    const float* __restrict__ hp, const float* __restrict__ pk,
    const float* __restrict__ adst, const int* __restrict__ P,
    const int* __restrict__ ssrc, const float* __restrict__ beta,
    const float* __restrict__ lin_w, const float* __restrict__ lin_b,
    float* __restrict__ out) {
  __shared__ __align__(16) float sLW[64 * 196];  // transposed lin_w: [c][j], stride 196
  int tid = threadIdx.x;
  for (int idx = tid; idx < 192 * 64; idx += 512) {
    int j = idx >> 6, c = idx & 63;
    sLW[c * 196 + j] = lin_w[idx];
  }
  __syncthreads();
  int lane = tid & 63, wid = tid >> 6;
  int g = blockIdx.x * 8 + wid;  // 4 nodes per wave
  int hgrp = lane >> 4;
  float y0 = lin_b[lane];
  float y[4] = {y0, y0, y0, y0};
  for (int r = 0; r < 3; r++) {
    float hr[4];
    float b1 = beta[r * 128 + 64 + lane];  // out-part of gate beta
    const float* __restrict__ hpr = hp + (size_t)r * N_NODES * 64;
    const float* __restrict__ pkr = pk + (size_t)r * N_NODES * 8;
#pragma unroll
    for (int i = 0; i < 4; i++) {
      int n = g * 4 + i;
      int idxrn = r * N_NODES + n;
      int beg = P[idxrn];
      int end = (idxrn + 1 < RN) ? P[idxrn + 1] : RE;
      float adh = adst[(size_t)idxrn * 4 + hgrp];
      float hpv = hp[(size_t)idxrn * 64 + lane];  // hoisted: overlaps edge loop
      float oa0 = 0.f, oa1 = 0.f, oa2 = 0.f, oa3 = 0.f;
      float ds0 = 0.f, ds1 = 0.f, ds2 = 0.f, ds3 = 0.f;
      float sd0 = 0.f, sd1 = 0.f, sd2 = 0.f, sd3 = 0.f;
      for (int e = beg; e < end; e += 4) {
        int rem = end - e;
        // inactive slots reuse s0: duplicate addresses coalesce, no extra traffic
        int s0 = ssrc[e];
        int s1 = (rem > 1) ? ssrc[e + 1] : s0;
        int s2 = (rem > 2) ? ssrc[e + 2] : s0;
        int s3 = (rem > 3) ? ssrc[e + 3] : s0;
        const float* p0 = pkr + (size_t)s0 * 8;
        const float* p1 = pkr + (size_t)s1 * 8;
        const float* p2 = pkr + (size_t)s2 * 8;
        const float* p3 = pkr + (size_t)s3 * 8;
        float av0 = p0[hgrp], av1 = p1[hgrp], av2 = p2[hgrp], av3 = p3[hgrp];
        float sv0 = p0[4], sv1 = p1[4], sv2 = p2[4], sv3 = p3[4];
        float hv0 = hpr[(size_t)s0 * 64 + lane];
        float hv1 = hpr[(size_t)s1 * 64 + lane];
        float hv2 = hpr[(size_t)s2 * 64 + lane];
        float hv3 = hpr[(size_t)s3 * 64 + lane];
        float a0 = av0 + adh; a0 = a0 >= 0.f ? a0 : 0.01f * a0;
        float a1 = av1 + adh; a1 = a1 >= 0.f ? a1 : 0.01f * a1;
        float a2 = av2 + adh; a2 = a2 >= 0.f ? a2 : 0.01f * a2;
        float a3 = av3 + adh; a3 = a3 >= 0.f ? a3 : 0.01f * a3;
        float ex0 = __expf(a0);
        float ex1 = (rem > 1) ? __expf(a1) : 0.f;
        float ex2 = (rem > 2) ? __expf(a2) : 0.f;
        float ex3 = (rem > 3) ? __expf(a3) : 0.f;
        sv1 = (rem > 1) ? sv1 : 0.f;
        sv2 = (rem > 2) ? sv2 : 0.f;
        sv3 = (rem > 3) ? sv3 : 0.f;
        oa0 += ex0 * hv0; ds0 += ex0; sd0 += sv0;
        oa1 += ex1 * hv1; ds1 += ex1; sd1 += sv1;
        oa2 += ex2 * hv2; ds2 += ex2; sd2 += sv2;
        oa3 += ex3 * hv3; ds3 += ex3; sd3 += sv3;
      }
      float oacc = (oa0 + oa1) + (oa2 + oa3);
      float dsum = (ds0 + ds1) + (ds2 + ds3);
      float sdac = (sd0 + sd1) + (sd2 + sd3);
      float ov = oacc / fmaxf(dsum, 1e-20f);
      float em = sdac / fmaxf((float)(end - beg), 1.f);  // wave-uniform gate es-part
      float gc = ov * b1;
#pragma unroll
      for (int m = 1; m < 64; m <<= 1) gc += __shfl_xor(gc, m);
      float gt = 1.f / (1.f + __expf(-(gc + em)));
      hr[i] = gt * ov + (1.f - gt) * hpv;
    }
    const float* wrow = &sLW[lane * 196 + r * 64];
#pragma unroll
    for (int j4 = 0; j4 < 64; j4 += 4) {
      float4 wv = *reinterpret_cast<const float4*>(wrow + j4);
#pragma unroll
      for (int i = 0; i < 4; i++) {
        y[i] += bcast(hr[i], j4) * wv.x + bcast(hr[i], j4 + 1) * wv.y +
                bcast(hr[i], j4 + 2) * wv.z + bcast(hr[i], j4 + 3) * wv.w;
      }
    }
  }
#pragma unroll
  for (int i = 0; i < 4; i++) out[(g * 4 + i) * 64 + lane] = y[i];
}

extern "C" void kernel_launch(void* const* d_in, const int* in_sizes, int n_in,
                              void* d_out, int out_size, void* d_ws, size_t ws_size,
                              hipStream_t stream) {
  const float* h = (const float*)d_in[0];
  const int* src = (const int*)d_in[1];
  const int* dst = (const int*)d_in[2];
  const float* d_w = (const float*)d_in[3];
  const float* d_b = (const float*)d_in[4];
  const float* w_w = (const float*)d_in[5];
  const float* w_b = (const float*)d_in[6];
  const float* atten_w = (const float*)d_in[7];
  const float* atten_b = (const float*)d_in[8];
  const float* beta = (const float*)d_in[9];
  const float* lin_w = (const float*)d_in[10];
  const float* lin_b = (const float*)d_in[11];
  float* out = (float*)d_out;

  float* ws = (float*)d_ws;
  float* hp = ws;                                      // R*N*64
  float* pk = hp + (size_t)R_REL * N_NODES * 64;       // R*N*8
  float* adst = pk + (size_t)R_REL * N_NODES * 8;      // R*N*4
  int* deg = (int*)(adst + (size_t)R_REL * N_NODES * 4);  // RN
  int* P = deg + RN;                                   // RN
  int* cursor = P + RN;                                // RN
  int* bsums = cursor + RN;                            // 256
  int* boffs = bsums + 256;                            // 256
  int* ssrc = boffs + 256;                             // RE

  int nb = (RN + 2047) / 2048;
  k_zero<<<(RN + 255) / 256, 256, 0, stream>>>(deg, RN);
  k_count<<<(RE + 255) / 256, 256, 0, stream>>>(dst, deg);
  k_scan1<<<nb, 256, 0, stream>>>(deg, P, bsums);
  k_scan2<<<1, 256, 0, stream>>>(bsums, boffs, nb);
  k_scan3<<<(RN + 255) / 256, 256, 0, stream>>>(P, cursor, boffs);
  k_scatter<<<(RE + 255) / 256, 256, 0, stream>>>(src, dst, cursor, ssrc);
  k_node<<<1024, 256, 0, stream>>>(h, d_w, d_b, w_w, w_b, atten_w, atten_b, beta,
                                   hp, pk, adst);
  k_fused<<<N_NODES / 32, 512, 0, stream>>>(hp, pk, adst, P, ssrc, beta, lin_w,
                                            lin_b, out);
}

// Round 2
// 923.984 us; speedup vs baseline: 1.3172x; 1.1495x over previous
//
#include <hip/hip_runtime.h>

#define N_NODES 100000
#define N_EDGES 1200000
#define R_REL 3
#define RN (R_REL * N_NODES)   // 300000
#define RE (R_REL * N_EDGES)   // 3600000

__device__ __forceinline__ float bcast(float v, int l) {
  return __int_as_float(__builtin_amdgcn_readlane(__float_as_int(v), l));
}

// ---------------- CSR build ----------------
__global__ void k_zero(int* p, int n) {
  int i = blockIdx.x * 256 + threadIdx.x;
  if (i < n) p[i] = 0;
}

__global__ void k_count(const int* __restrict__ dst, int* __restrict__ deg) {
  int i = blockIdx.x * 256 + threadIdx.x;
  if (i < RE) {
    int r = i / N_EDGES;
    atomicAdd(&deg[r * N_NODES + dst[i]], 1);
  }
}

__global__ void k_scan1(const int* __restrict__ deg, int* __restrict__ P,
                        int* __restrict__ bsums) {
  __shared__ int sd[256];
  int t = threadIdx.x;
  int base = blockIdx.x * 2048 + t * 8;
  int v[8];
  int tot = 0;
#pragma unroll
  for (int q = 0; q < 8; q++) {
    v[q] = (base + q < RN) ? deg[base + q] : 0;
    tot += v[q];
  }
  sd[t] = tot;
  __syncthreads();
  for (int off = 1; off < 256; off <<= 1) {
    int x = (t >= off) ? sd[t - off] : 0;
    __syncthreads();
    sd[t] += x;
    __syncthreads();
  }
  int run = sd[t] - tot;  // exclusive prefix within chunk
#pragma unroll
  for (int q = 0; q < 8; q++) {
    if (base + q < RN) P[base + q] = run;
    run += v[q];
  }
  if (t == 255) bsums[blockIdx.x] = sd[255];
}

__global__ void k_scan2(const int* __restrict__ bsums, int* __restrict__ boffs, int nb) {
  __shared__ int sd[256];
  int t = threadIdx.x;
  int v = (t < nb) ? bsums[t] : 0;
  sd[t] = v;
  __syncthreads();
  for (int off = 1; off < 256; off <<= 1) {
    int x = (t >= off) ? sd[t - off] : 0;
    __syncthreads();
    sd[t] += x;
    __syncthreads();
  }
  if (t < nb) boffs[t] = sd[t] - v;
}

__global__ void k_scan3(int* __restrict__ P, int* __restrict__ cursor,
                        const int* __restrict__ boffs) {
  int i = blockIdx.x * 256 + threadIdx.x;
  if (i < RN) {
    int p = P[i] + boffs[i >> 11];
    P[i] = p;
    cursor[i] = p;
  }
}

__global__ void k_scatter(const int* __restrict__ src, const int* __restrict__ dst,
                          int* __restrict__ cursor, int* __restrict__ ssrc) {
  int i = blockIdx.x * 256 + threadIdx.x;
  if (i < RE) {
    int r = i / N_EDGES;
    int p = atomicAdd(&cursor[r * N_NODES + dst[i]], 1);
    ssrc[p] = src[i];
  }
}

// ---------------- node transforms ----------------
// hp[r][n][64] = h@w_w[r]+w_b[r]
// pk[r][n][8]  = { asrc[4 heads], sdot, -, -, - }  (32B packed per (r,n))
//   asrc[h] = dot(hp_head, wa0) + dot(es_head, wa2) + atten_b[r]
//   sdot    = dot(es[n], beta_r[0:64])   (gate es-part, distributed over seg-sum)
// adst[r][n][4] = per-head dst attention part
__global__ __launch_bounds__(256) void k_node(
    const float* __restrict__ h, const float* __restrict__ d_w,
    const float* __restrict__ d_b, const float* __restrict__ w_w,
    const float* __restrict__ w_b, const float* __restrict__ atten_w,
    const float* __restrict__ atten_b, const float* __restrict__ beta,
    float* __restrict__ hp, float* __restrict__ pk, float* __restrict__ adst) {
  __shared__ float sW[4 * 4096];  // 64 KB: d_w, w_w[0..2], layout [m][k*64+c]
  int tid = threadIdx.x;
  for (int idx = tid; idx < 4096; idx += 256) {
    sW[idx] = d_w[idx];
    sW[4096 + idx] = w_w[idx];
    sW[8192 + idx] = w_w[4096 + idx];
    sW[12288 + idx] = w_w[8192 + idx];
  }
  __syncthreads();
  int lane = tid & 63, wid = tid >> 6;
  int wave = blockIdx.x * 4 + wid, nw = gridDim.x * 4;
  int k16 = lane & 15, hgrp = lane >> 4;
  float dbv = d_b[lane];
  float wbv0 = w_b[lane], wbv1 = w_b[64 + lane], wbv2 = w_b[128 + lane];
  float wa0[3], wa1[3], wa2[3], ab[3], bb[3];
#pragma unroll
  for (int r = 0; r < 3; r++) {
    wa0[r] = atten_w[r * 48 + k16];
    wa1[r] = atten_w[r * 48 + 16 + k16];
    wa2[r] = atten_w[r * 48 + 32 + k16];
    ab[r] = atten_b[r];
    bb[r] = beta[r * 128 + lane];  // es-part of gate beta
  }
  for (int g = wave; g < N_NODES / 8; g += nw) {
    int n0 = g * 8;
    float hr[8];
#pragma unroll
    for (int i = 0; i < 8; i++) hr[i] = h[(n0 + i) * 64 + lane];
    float acc[8][4];
#pragma unroll
    for (int i = 0; i < 8; i++) {
      acc[i][0] = dbv; acc[i][1] = wbv0; acc[i][2] = wbv1; acc[i][3] = wbv2;
    }
#pragma unroll 4
    for (int k = 0; k < 64; k++) {
      float w0 = sW[k * 64 + lane];
      float w1 = sW[4096 + k * 64 + lane];
      float w2 = sW[8192 + k * 64 + lane];
      float w3 = sW[12288 + k * 64 + lane];
#pragma unroll
      for (int i = 0; i < 8; i++) {
        float a = bcast(hr[i], k);
        acc[i][0] += a * w0; acc[i][1] += a * w1;
        acc[i][2] += a * w2; acc[i][3] += a * w3;
      }
    }
#pragma unroll
    for (int i = 0; i < 8; i++) {
      int n = n0 + i;
      float esv = tanhf(2.f * acc[i][0]);
#pragma unroll
      for (int r = 0; r < 3; r++) {
        int idxrn = r * N_NODES + n;
        float hpv = acc[i][1 + r];
        hp[(size_t)idxrn * 64 + lane] = hpv;
        float cs = hpv * wa0[r] + esv * wa2[r];
        float cd = hpv * wa1[r];
#pragma unroll
        for (int m = 1; m < 16; m <<= 1) {
          cs += __shfl_xor(cs, m);
          cd += __shfl_xor(cd, m);
        }
        float sv = esv * bb[r];
#pragma unroll
        for (int m = 1; m < 64; m <<= 1) sv += __shfl_xor(sv, m);
        if (k16 == 0) {
          pk[(size_t)idxrn * 8 + hgrp] = cs + ab[r];
          adst[(size_t)idxrn * 4 + hgrp] = cd;
        }
        if (lane == 0) pk[(size_t)idxrn * 8 + 4] = sv;
      }
    }
  }
}

// ---------------- fused: per-dst softmax-aggregate + gate + final linear ----------------
// Lane layout in the edge loop: slot = lane>>4 (one of 4 concurrent edges),
// c16 = lane&15 owns channels [c16*4, c16*4+3] (float4 of the hp row), head = c16>>2.
// Per 4 edges each lane does ONE edge's work -> ~4x fewer VALU/load instrs than
// the all-lanes-walk-every-edge layout. Cross-slot combine via shfl_xor(16|32).
#define EDGE_BODY(EE, OA, DS, SD)                                        \
  {                                                                      \
    int s_ = ssrc[EE];                                                   \
    int pb_ = s_ * 8;                                                    \
    float av_ = pkr[pb_ + head];                                         \
    float sv_ = pkr[pb_ + 4];                                            \
    float4 hv_ = *reinterpret_cast<const float4*>(&hpr[s_ * 64 + cq]);   \
    float a_ = av_ + adh;                                                \
    a_ = a_ >= 0.f ? a_ : 0.01f * a_;                                    \
    float ex_ = __expf(a_);                                              \
    OA.x += ex_ * hv_.x;                                                 \
    OA.y += ex_ * hv_.y;                                                 \
    OA.z += ex_ * hv_.z;                                                 \
    OA.w += ex_ * hv_.w;                                                 \
    DS += ex_;                                                           \
    SD += sv_;                                                           \
  }

__global__ __launch_bounds__(512) void k_fused(
    const float* __restrict__ hp, const float* __restrict__ pk,
    const float* __restrict__ adst, const int* __restrict__ P,
    const int* __restrict__ ssrc, const float* __restrict__ beta,
    const float* __restrict__ lin_w, const float* __restrict__ lin_b,
    float* __restrict__ out) {
  __shared__ __align__(16) float sLW[64 * 196];  // transposed lin_w: [c][j], stride 196
  int tid = threadIdx.x;
  for (int idx = tid; idx < 192 * 64; idx += 512) {
    int j = idx >> 6, c = idx & 63;
    sLW[c * 196 + j] = lin_w[idx];
  }
  __syncthreads();
  int lane = tid & 63, wid = tid >> 6;
  int g = blockIdx.x * 8 + wid;  // 4 nodes per wave
  int slot = lane >> 4;          // edge slot 0..3
  int c16 = lane & 15;           // channel-quad index
  int cq = c16 * 4;              // first channel of this lane's quad
  int head = c16 >> 2;           // head of these 4 channels
  float y0 = lin_b[lane];
  float y[4] = {y0, y0, y0, y0};
  for (int r = 0; r < 3; r++) {
    const float* __restrict__ hpr = hp + (size_t)r * N_NODES * 64;
    const float* __restrict__ pkr = pk + (size_t)r * N_NODES * 8;
    float4 b1v = *reinterpret_cast<const float4*>(&beta[r * 128 + 64 + cq]);
    float4 hr4[4];
#pragma unroll
    for (int i = 0; i < 4; i++) {
      int n = g * 4 + i;
      int idxrn = r * N_NODES + n;
      int beg = P[idxrn];
      int end = (idxrn + 1 < RN) ? P[idxrn + 1] : RE;
      float adh = adst[idxrn * 4 + head];
      float4 hpv = *reinterpret_cast<const float4*>(&hpr[n * 64 + cq]);
      float4 oaA = {0.f, 0.f, 0.f, 0.f}, oaB = {0.f, 0.f, 0.f, 0.f};
      float dsA = 0.f, dsB = 0.f, sdA = 0.f, sdB = 0.f;
      int e = beg + slot;
      for (; e + 4 < end; e += 8) {
        EDGE_BODY(e, oaA, dsA, sdA);
        EDGE_BODY(e + 4, oaB, dsB, sdB);
      }
      if (e < end) EDGE_BODY(e, oaA, dsA, sdA);
      float4 oa;
      oa.x = oaA.x + oaB.x;
      oa.y = oaA.y + oaB.y;
      oa.z = oaA.z + oaB.z;
      oa.w = oaA.w + oaB.w;
      float ds = dsA + dsB, sd = sdA + sdB;
      // combine the 4 edge slots (lane bits 4,5)
      oa.x += __shfl_xor(oa.x, 16); oa.x += __shfl_xor(oa.x, 32);
      oa.y += __shfl_xor(oa.y, 16); oa.y += __shfl_xor(oa.y, 32);
      oa.z += __shfl_xor(oa.z, 16); oa.z += __shfl_xor(oa.z, 32);
      oa.w += __shfl_xor(oa.w, 16); oa.w += __shfl_xor(oa.w, 32);
      ds += __shfl_xor(ds, 16); ds += __shfl_xor(ds, 32);
      sd += __shfl_xor(sd, 16); sd += __shfl_xor(sd, 32);
      float inv = 1.f / fmaxf(ds, 1e-20f);
      float4 ov;
      ov.x = oa.x * inv; ov.y = oa.y * inv; ov.z = oa.z * inv; ov.w = oa.w * inv;
      float em = sd / fmaxf((float)(end - beg), 1.f);  // wave-uniform gate es-part
      float gc = ov.x * b1v.x + ov.y * b1v.y + ov.z * b1v.z + ov.w * b1v.w;
      // reduce over the 16 channel-quads (slots hold duplicates, don't sum them)
      gc += __shfl_xor(gc, 1); gc += __shfl_xor(gc, 2);
      gc += __shfl_xor(gc, 4); gc += __shfl_xor(gc, 8);
      float gt = 1.f / (1.f + __expf(-(gc + em)));
      float4 hrv;
      hrv.x = gt * ov.x + (1.f - gt) * hpv.x;
      hrv.y = gt * ov.y + (1.f - gt) * hpv.y;
      hrv.z = gt * ov.z + (1.f - gt) * hpv.z;
      hrv.w = gt * ov.w + (1.f - gt) * hpv.w;
      hr4[i] = hrv;
    }
    const float* wrow = &sLW[lane * 196 + r * 64];
#pragma unroll
    for (int j4 = 0; j4 < 64; j4 += 4) {
      float4 wv = *reinterpret_cast<const float4*>(wrow + j4);
      const int sl = j4 >> 2;  // lane holding channels j4..j4+3 (words x..w)
#pragma unroll
      for (int i = 0; i < 4; i++) {
        y[i] += bcast(hr4[i].x, sl) * wv.x + bcast(hr4[i].y, sl) * wv.y +
                bcast(hr4[i].z, sl) * wv.z + bcast(hr4[i].w, sl) * wv.w;
      }
    }
  }
#pragma unroll
  for (int i = 0; i < 4; i++) out[(g * 4 + i) * 64 + lane] = y[i];
}

extern "C" void kernel_launch(void* const* d_in, const int* in_sizes, int n_in,
                              void* d_out, int out_size, void* d_ws, size_t ws_size,
                              hipStream_t stream) {
  const float* h = (const float*)d_in[0];
  const int* src = (const int*)d_in[1];
  const int* dst = (const int*)d_in[2];
  const float* d_w = (const float*)d_in[3];
  const float* d_b = (const float*)d_in[4];
  const float* w_w = (const float*)d_in[5];
  const float* w_b = (const float*)d_in[6];
  const float* atten_w = (const float*)d_in[7];
  const float* atten_b = (const float*)d_in[8];
  const float* beta = (const float*)d_in[9];
  const float* lin_w = (const float*)d_in[10];
  const float* lin_b = (const float*)d_in[11];
  float* out = (float*)d_out;

  float* ws = (float*)d_ws;
  float* hp = ws;                                      // R*N*64
  float* pk = hp + (size_t)R_REL * N_NODES * 64;       // R*N*8
  float* adst = pk + (size_t)R_REL * N_NODES * 8;      // R*N*4
  int* deg = (int*)(adst + (size_t)R_REL * N_NODES * 4);  // RN
  int* P = deg + RN;                                   // RN
  int* cursor = P + RN;                                // RN
  int* bsums = cursor + RN;                            // 256
  int* boffs = bsums + 256;                            // 256
  int* ssrc = boffs + 256;                             // RE

  int nb = (RN + 2047) / 2048;
  k_zero<<<(RN + 255) / 256, 256, 0, stream>>>(deg, RN);
  k_count<<<(RE + 255) / 256, 256, 0, stream>>>(dst, deg);
  k_scan1<<<nb, 256, 0, stream>>>(deg, P, bsums);
  k_scan2<<<1, 256, 0, stream>>>(bsums, boffs, nb);
  k_scan3<<<(RN + 255) / 256, 256, 0, stream>>>(P, cursor, boffs);
  k_scatter<<<(RE + 255) / 256, 256, 0, stream>>>(src, dst, cursor, ssrc);
  k_node<<<1024, 256, 0, stream>>>(h, d_w, d_b, w_w, w_b, atten_w, atten_b, beta,
                                   hp, pk, adst);
  k_fused<<<N_NODES / 32, 512, 0, stream>>>(hp, pk, adst, P, ssrc, beta, lin_w,
                                            lin_b, out);
}

// Round 4
// 584.297 us; speedup vs baseline: 2.0829x; 1.5814x over previous
//
#include <hip/hip_runtime.h>

#define N_NODES 100000
#define N_EDGES 1200000
#define R_REL 3
#define RN (R_REL * N_NODES)   // 300000
#define RE (R_REL * N_EDGES)   // 3600000

// bucket sort params
#define B_BITS 9
#define W_BKT 512                       // nodes per bucket
#define NB_R 196                        // ceil(N_NODES / W_BKT)
#define K_BKT (R_REL * NB_R)            // 588 buckets
#define TILE_A 8192
#define NBLK_A ((RE + TILE_A - 1) / TILE_A)  // 440

__device__ __forceinline__ float bcast(float v, int l) {
  return __int_as_float(__builtin_amdgcn_readlane(__float_as_int(v), l));
}

__device__ __forceinline__ int rel_of(int e) {
  return (e >= 2 * N_EDGES) ? 2 : (e >= N_EDGES ? 1 : 0);
}

__global__ void k_zero(int* p, int n) {
  int i = blockIdx.x * 256 + threadIdx.x;
  if (i < n) p[i] = 0;
}

// ---------------- CSR build: two-level LDS-staged counting sort ----------------
// Pass 1: per-tile LDS histogram over 588 coarse buckets -> global totals
__global__ __launch_bounds__(256) void k_hist(const int* __restrict__ dst,
                                              int* __restrict__ tot) {
  __shared__ int sh[K_BKT];
  int tid = threadIdx.x;
  for (int i = tid; i < K_BKT; i += 256) sh[i] = 0;
  __syncthreads();
  int base = blockIdx.x * TILE_A;
  int end = min(base + TILE_A, RE);
  for (int e = base + tid; e < end; e += 256) {
    atomicAdd(&sh[rel_of(e) * NB_R + (dst[e] >> B_BITS)], 1);
  }
  __syncthreads();
  for (int i = tid; i < K_BKT; i += 256) {
    int c = sh[i];
    if (c) atomicAdd(&tot[i], c);
  }
}

// Pass 2: exclusive scan of 588 bucket totals -> bucket bases BB + global cursors
__global__ void k_scanK(const int* __restrict__ tot, int* __restrict__ BB,
                        int* __restrict__ cursor) {
  __shared__ int sd[256];
  int t = threadIdx.x;
  int v[3];
  int tots = 0;
#pragma unroll
  for (int q = 0; q < 3; q++) {
    int k = t * 3 + q;
    v[q] = (k < K_BKT) ? tot[k] : 0;
    tots += v[q];
  }
  sd[t] = tots;
  __syncthreads();
  for (int off = 1; off < 256; off <<= 1) {
    int x = (t >= off) ? sd[t - off] : 0;
    __syncthreads();
    sd[t] += x;
    __syncthreads();
  }
  int run = sd[t] - tots;
#pragma unroll
  for (int q = 0; q < 3; q++) {
    int k = t * 3 + q;
    if (k < K_BKT) {
      BB[k] = run;
      cursor[k] = run;
    }
    run += v[q];
  }
  if (t == 255) BB[K_BKT] = RE;
}

// Pass 3: scatter packed records (src<<9 | dst&511) into bucket-contiguous regions.
// One atomic-return per (block,bucket) instead of per edge; placement via LDS cursors.
// A block's writes per bucket are contiguous runs -> L2 lines fill before writeback.
__global__ __launch_bounds__(256) void k_scatterA(const int* __restrict__ src,
                                                  const int* __restrict__ dst,
                                                  int* __restrict__ cursor,
                                                  unsigned int* __restrict__ rec) {
  __shared__ int sh[K_BKT];
  int tid = threadIdx.x;
  for (int i = tid; i < K_BKT; i += 256) sh[i] = 0;
  __syncthreads();
  int base = blockIdx.x * TILE_A;
  int end = min(base + TILE_A, RE);
  for (int e = base + tid; e < end; e += 256) {
    atomicAdd(&sh[rel_of(e) * NB_R + (dst[e] >> B_BITS)], 1);
  }
  __syncthreads();
  for (int i = tid; i < K_BKT; i += 256) {
    int c = sh[i];
    sh[i] = c ? atomicAdd(&cursor[i], c) : 0;  // own slot: no cross-thread hazard
  }
  __syncthreads();
  for (int e = base + tid; e < end; e += 256) {
    int d = dst[e];
    int k = rel_of(e) * NB_R + (d >> B_BITS);
    int p = atomicAdd(&sh[k], 1);
    rec[p] = ((unsigned)src[e] << B_BITS) | (unsigned)(d & (W_BKT - 1));
  }
}

// Pass 4: per-bucket counting sort (512 node slots in LDS) -> P (CSR offsets) + ssrc.
// Bucket region (~26 KB) stays L2-resident; scattered stores fill lines in place.
__global__ __launch_bounds__(256) void k_bsort(const unsigned int* __restrict__ rec,
                                               const int* __restrict__ BB,
                                               int* __restrict__ P,
                                               int* __restrict__ ssrc) {
  __shared__ int cnt[W_BKT];
  __shared__ int sd[256];
  int kb = blockIdx.x;
  int r = kb / NB_R;
  int nb0 = (kb % NB_R) * W_BKT;  // first node (within relation) of this bucket
  int beg = BB[kb], end = BB[kb + 1];
  int tid = threadIdx.x;
  cnt[tid] = 0;
  cnt[256 + tid] = 0;
  __syncthreads();
  for (int e = beg + tid; e < end; e += 256)
    atomicAdd(&cnt[rec[e] & (W_BKT - 1)], 1);
  __syncthreads();
  // block exclusive scan over 512 (2 elements per thread)
  int v0 = cnt[2 * tid], v1 = cnt[2 * tid + 1];
  int tot2 = v0 + v1;
  sd[tid] = tot2;
  __syncthreads();
  for (int off = 1; off < 256; off <<= 1) {
    int x = (tid >= off) ? sd[tid - off] : 0;
    __syncthreads();
    sd[tid] += x;
    __syncthreads();
  }
  int run = sd[tid] - tot2;
  int node0 = nb0 + 2 * tid;
  int pbase = r * N_NODES + node0;
  if (node0 < N_NODES) P[pbase] = beg + run;
  if (node0 + 1 < N_NODES) P[pbase + 1] = beg + run + v0;
  // reuse cnt as per-node cursors (all threads already read their cnt slots)
  cnt[2 * tid] = beg + run;
  cnt[2 * tid + 1] = beg + run + v0;
  __syncthreads();
  for (int e = beg + tid; e < end; e += 256) {
    unsigned rc = rec[e];
    int p = atomicAdd(&cnt[rc & (W_BKT - 1)], 1);
    ssrc[p] = (int)(rc >> B_BITS);
  }
}

// ---------------- node transforms ----------------
// hp[r][n][64] = h@w_w[r]+w_b[r]
// pk[r][n][8]  = { asrc[4 heads], sdot, -, -, - }  (32B packed per (r,n))
//   asrc[h] = dot(hp_head, wa0) + dot(es_head, wa2) + atten_b[r]
//   sdot    = dot(es[n], beta_r[0:64])   (gate es-part, distributed over seg-sum)
// adst[r][n][4] = per-head dst attention part
__global__ __launch_bounds__(256) void k_node(
    const float* __restrict__ h, const float* __restrict__ d_w,
    const float* __restrict__ d_b, const float* __restrict__ w_w,
    const float* __restrict__ w_b, const float* __restrict__ atten_w,
    const float* __restrict__ atten_b, const float* __restrict__ beta,
    float* __restrict__ hp, float* __restrict__ pk, float* __restrict__ adst) {
  __shared__ float sW[4 * 4096];  // 64 KB: d_w, w_w[0..2], layout [m][k*64+c]
  int tid = threadIdx.x;
  for (int idx = tid; idx < 4096; idx += 256) {
    sW[idx] = d_w[idx];
    sW[4096 + idx] = w_w[idx];
    sW[8192 + idx] = w_w[4096 + idx];
    sW[12288 + idx] = w_w[8192 + idx];
  }
  __syncthreads();
  int lane = tid & 63, wid = tid >> 6;
  int wave = blockIdx.x * 4 + wid, nw = gridDim.x * 4;
  int k16 = lane & 15, hgrp = lane >> 4;
  float dbv = d_b[lane];
  float wbv0 = w_b[lane], wbv1 = w_b[64 + lane], wbv2 = w_b[128 + lane];
  float wa0[3], wa1[3], wa2[3], ab[3], bb[3];
#pragma unroll
  for (int r = 0; r < 3; r++) {
    wa0[r] = atten_w[r * 48 + k16];
    wa1[r] = atten_w[r * 48 + 16 + k16];
    wa2[r] = atten_w[r * 48 + 32 + k16];
    ab[r] = atten_b[r];
    bb[r] = beta[r * 128 + lane];  // es-part of gate beta
  }
  for (int g = wave; g < N_NODES / 8; g += nw) {
    int n0 = g * 8;
    float hr[8];
#pragma unroll
    for (int i = 0; i < 8; i++) hr[i] = h[(n0 + i) * 64 + lane];
    float acc[8][4];
#pragma unroll
    for (int i = 0; i < 8; i++) {
      acc[i][0] = dbv; acc[i][1] = wbv0; acc[i][2] = wbv1; acc[i][3] = wbv2;
    }
#pragma unroll 4
    for (int k = 0; k < 64; k++) {
      float w0 = sW[k * 64 + lane];
      float w1 = sW[4096 + k * 64 + lane];
      float w2 = sW[8192 + k * 64 + lane];
      float w3 = sW[12288 + k * 64 + lane];
#pragma unroll
      for (int i = 0; i < 8; i++) {
        float a = bcast(hr[i], k);
        acc[i][0] += a * w0; acc[i][1] += a * w1;
        acc[i][2] += a * w2; acc[i][3] += a * w3;
      }
    }
#pragma unroll
    for (int i = 0; i < 8; i++) {
      int n = n0 + i;
      float esv = tanhf(2.f * acc[i][0]);
#pragma unroll
      for (int r = 0; r < 3; r++) {
        int idxrn = r * N_NODES + n;
        float hpv = acc[i][1 + r];
        hp[(size_t)idxrn * 64 + lane] = hpv;
        float cs = hpv * wa0[r] + esv * wa2[r];
        float cd = hpv * wa1[r];
#pragma unroll
        for (int m = 1; m < 16; m <<= 1) {
          cs += __shfl_xor(cs, m);
          cd += __shfl_xor(cd, m);
        }
        float sv = esv * bb[r];
#pragma unroll
        for (int m = 1; m < 64; m <<= 1) sv += __shfl_xor(sv, m);
        if (k16 == 0) {
          pk[(size_t)idxrn * 8 + hgrp] = cs + ab[r];
          adst[(size_t)idxrn * 4 + hgrp] = cd;
        }
        if (lane == 0) pk[(size_t)idxrn * 8 + 4] = sv;
      }
    }
  }
}

// ---------------- fused: per-dst softmax-aggregate + gate + final linear ----------------
// Lane layout in the edge loop: slot = lane>>4 (one of 4 concurrent edges),
// c16 = lane&15 owns channels [c16*4, c16*4+3] (float4 of the hp row), head = c16>>2.
#define EDGE_BODY(EE, OA, DS, SD)                                        \
  {                                                                      \
    int s_ = ssrc[EE];                                                   \
    int pb_ = s_ * 8;                                                    \
    float av_ = pkr[pb_ + head];                                         \
    float sv_ = pkr[pb_ + 4];                                            \
    float4 hv_ = *reinterpret_cast<const float4*>(&hpr[s_ * 64 + cq]);   \
    float a_ = av_ + adh;                                                \
    a_ = a_ >= 0.f ? a_ : 0.01f * a_;                                    \
    float ex_ = __expf(a_);                                              \
    OA.x += ex_ * hv_.x;                                                 \
    OA.y += ex_ * hv_.y;                                                 \
    OA.z += ex_ * hv_.z;                                                 \
    OA.w += ex_ * hv_.w;                                                 \
    DS += ex_;                                                           \
    SD += sv_;                                                           \
  }

__global__ __launch_bounds__(512) void k_fused(
    const float* __restrict__ hp, const float* __restrict__ pk,
    const float* __restrict__ adst, const int* __restrict__ P,
    const int* __restrict__ ssrc, const float* __restrict__ beta,
    const float* __restrict__ lin_w, const float* __restrict__ lin_b,
    float* __restrict__ out) {
  __shared__ __align__(16) float sLW[64 * 196];  // transposed lin_w: [c][j], stride 196
  int tid = threadIdx.x;
  for (int idx = tid; idx < 192 * 64; idx += 512) {
    int j = idx >> 6, c = idx & 63;
    sLW[c * 196 + j] = lin_w[idx];
  }
  __syncthreads();
  int lane = tid & 63, wid = tid >> 6;
  int g = blockIdx.x * 8 + wid;  // 4 nodes per wave
  int slot = lane >> 4;          // edge slot 0..3
  int c16 = lane & 15;           // channel-quad index
  int cq = c16 * 4;              // first channel of this lane's quad
  int head = c16 >> 2;           // head of these 4 channels
  float y0 = lin_b[lane];
  float y[4] = {y0, y0, y0, y0};
  for (int r = 0; r < 3; r++) {
    const float* __restrict__ hpr = hp + (size_t)r * N_NODES * 64;
    const float* __restrict__ pkr = pk + (size_t)r * N_NODES * 8;
    float4 b1v = *reinterpret_cast<const float4*>(&beta[r * 128 + 64 + cq]);
    float4 hr4[4];
#pragma unroll
    for (int i = 0; i < 4; i++) {
      int n = g * 4 + i;
      int idxrn = r * N_NODES + n;
      int beg = P[idxrn];
      int end = (idxrn + 1 < RN) ? P[idxrn + 1] : RE;
      float adh = adst[idxrn * 4 + head];
      float4 hpv = *reinterpret_cast<const float4*>(&hpr[n * 64 + cq]);
      float4 oaA = {0.f, 0.f, 0.f, 0.f}, oaB = {0.f, 0.f, 0.f, 0.f};
      float dsA = 0.f, dsB = 0.f, sdA = 0.f, sdB = 0.f;
      int e = beg + slot;
      for (; e + 4 < end; e += 8) {
        EDGE_BODY(e, oaA, dsA, sdA);
        EDGE_BODY(e + 4, oaB, dsB, sdB);
      }
      if (e < end) EDGE_BODY(e, oaA, dsA, sdA);
      float4 oa;
      oa.x = oaA.x + oaB.x;
      oa.y = oaA.y + oaB.y;
      oa.z = oaA.z + oaB.z;
      oa.w = oaA.w + oaB.w;
      float ds = dsA + dsB, sd = sdA + sdB;
      // combine the 4 edge slots (lane bits 4,5)
      oa.x += __shfl_xor(oa.x, 16); oa.x += __shfl_xor(oa.x, 32);
      oa.y += __shfl_xor(oa.y, 16); oa.y += __shfl_xor(oa.y, 32);
      oa.z += __shfl_xor(oa.z, 16); oa.z += __shfl_xor(oa.z, 32);
      oa.w += __shfl_xor(oa.w, 16); oa.w += __shfl_xor(oa.w, 32);
      ds += __shfl_xor(ds, 16); ds += __shfl_xor(ds, 32);
      sd += __shfl_xor(sd, 16); sd += __shfl_xor(sd, 32);
      float inv = 1.f / fmaxf(ds, 1e-20f);
      float4 ov;
      ov.x = oa.x * inv; ov.y = oa.y * inv; ov.z = oa.z * inv; ov.w = oa.w * inv;
      float em = sd / fmaxf((float)(end - beg), 1.f);  // wave-uniform gate es-part
      float gc = ov.x * b1v.x + ov.y * b1v.y + ov.z * b1v.z + ov.w * b1v.w;
      gc += __shfl_xor(gc, 1); gc += __shfl_xor(gc, 2);
      gc += __shfl_xor(gc, 4); gc += __shfl_xor(gc, 8);
      float gt = 1.f / (1.f + __expf(-(gc + em)));
      float4 hrv;
      hrv.x = gt * ov.x + (1.f - gt) * hpv.x;
      hrv.y = gt * ov.y + (1.f - gt) * hpv.y;
      hrv.z = gt * ov.z + (1.f - gt) * hpv.z;
      hrv.w = gt * ov.w + (1.f - gt) * hpv.w;
      hr4[i] = hrv;
    }
    const float* wrow = &sLW[lane * 196 + r * 64];
#pragma unroll
    for (int j4 = 0; j4 < 64; j4 += 4) {
      float4 wv = *reinterpret_cast<const float4*>(wrow + j4);
      const int sl = j4 >> 2;  // lane holding channels j4..j4+3 (words x..w)
#pragma unroll
      for (int i = 0; i < 4; i++) {
        y[i] += bcast(hr4[i].x, sl) * wv.x + bcast(hr4[i].y, sl) * wv.y +
                bcast(hr4[i].z, sl) * wv.z + bcast(hr4[i].w, sl) * wv.w;
      }
    }
  }
#pragma unroll
  for (int i = 0; i < 4; i++) out[(g * 4 + i) * 64 + lane] = y[i];
}

extern "C" void kernel_launch(void* const* d_in, const int* in_sizes, int n_in,
                              void* d_out, int out_size, void* d_ws, size_t ws_size,
                              hipStream_t stream) {
  const float* h = (const float*)d_in[0];
  const int* src = (const int*)d_in[1];
  const int* dst = (const int*)d_in[2];
  const float* d_w = (const float*)d_in[3];
  const float* d_b = (const float*)d_in[4];
  const float* w_w = (const float*)d_in[5];
  const float* w_b = (const float*)d_in[6];
  const float* atten_w = (const float*)d_in[7];
  const float* atten_b = (const float*)d_in[8];
  const float* beta = (const float*)d_in[9];
  const float* lin_w = (const float*)d_in[10];
  const float* lin_b = (const float*)d_in[11];
  float* out = (float*)d_out;

  float* ws = (float*)d_ws;
  float* hp = ws;                                      // R*N*64
  float* pk = hp + (size_t)R_REL * N_NODES * 64;       // R*N*8
  float* adst = pk + (size_t)R_REL * N_NODES * 8;      // R*N*4
  int* P = (int*)(adst + (size_t)R_REL * N_NODES * 4); // RN
  int* ssrc = P + RN;                                  // RE
  unsigned int* rec = (unsigned int*)(ssrc + RE);      // RE
  int* tot = (int*)(rec + RE);                         // K_BKT
  int* BB = tot + K_BKT;                               // K_BKT+1
  int* cursor = BB + K_BKT + 1;                        // K_BKT

  k_zero<<<(K_BKT + 255) / 256, 256, 0, stream>>>(tot, K_BKT);
  k_hist<<<NBLK_A, 256, 0, stream>>>(dst, tot);
  k_scanK<<<1, 256, 0, stream>>>(tot, BB, cursor);
  k_scatterA<<<NBLK_A, 256, 0, stream>>>(src, dst, cursor, rec);
  k_bsort<<<K_BKT, 256, 0, stream>>>(rec, BB, P, ssrc);
  k_node<<<1024, 256, 0, stream>>>(h, d_w, d_b, w_w, w_b, atten_w, atten_b, beta,
                                   hp, pk, adst);
  k_fused<<<N_NODES / 32, 512, 0, stream>>>(hp, pk, adst, P, ssrc, beta, lin_w,
                                            lin_b, out);
}